// Round 15
// baseline (216.576 us; speedup 1.0000x reference)
//
#include <hip/hip_runtime.h>
#include <hip/hip_bf16.h>
#include <math.h>

// Problem constants (fixed by setup_inputs)
#define NB 4
#define LQ 300
#define CDIM 256
#define NH 8
#define DH 32
#define NL 4
#define NP 4
#define ROI_ 7
#define LEN_IN 19947
#define H0 100
#define W0 150
#define ROI_DIM (ROI_*ROI_*CDIM)   // 12544
#define NQ_TOT (NB*LQ)             // 1200
#define QPB 3                      // queries per block in fallback K2

// K2b GEMM config
#define MPAD2 1280                 // 10 * 128
#define NDIM 384
#define KCH_TOT 196                // 12544 / 64
#define MT_N 10                    // MPAD2/128
#define NT_N 3                     // NDIM/128

// K1 GEMM config
#define VTOT (NB*LEN_IN)           // 79788
#define VMT  624                   // ceil(79788/128)

__device__ __constant__ int d_HL[4] = {100, 50, 25, 13};
__device__ __constant__ int d_WL[4] = {150, 75, 38, 19};
__device__ __constant__ int d_ST[4] = {0, 15000, 18750, 19700};

typedef __attribute__((ext_vector_type(8))) short short8;
typedef __attribute__((ext_vector_type(4))) float f32x4;

__device__ __forceinline__ unsigned short f2bf(float f) {
    unsigned int u = __float_as_uint(f);
    unsigned int r = (u + 0x7fffu + ((u >> 16) & 1u)) >> 16;
    return (unsigned short)r;
}
__device__ __forceinline__ float bf2f(unsigned short s) {
    return __uint_as_float(((unsigned int)s) << 16);
}

// HBM -> LDS direct copy, 16B per lane (global_load_lds_dwordx4).
__device__ __forceinline__ void gld16(const void* g, void* l) {
    __builtin_amdgcn_global_load_lds(
        (const __attribute__((address_space(1))) unsigned int*)g,
        (__attribute__((address_space(3))) unsigned int*)l, 16, 0, 0);
}

// 8-wave inner loop: one 128x128 block-tile K-step (K=64), wave tile 32x64,
// hi/lo bf16 in LDS (XOR-swizzled), 3-product accumulate. acc = 32 VGPRs.
__device__ __forceinline__ void mfma_32x64(
    const unsigned short* aH, const unsigned short* aL,
    const unsigned short* bH, const unsigned short* bL,
    int wm, int wn, int lr, int kb, f32x4 acc[2][4])
{
    #pragma unroll
    for (int kk = 0; kk < 2; ++kk) {
        short8 ah[2], al[2];
        #pragma unroll
        for (int i = 0; i < 2; ++i) {
            int row = wm * 32 + i * 16 + lr;
            int off = (row * 128 + kk * 64 + kb * 16) ^ ((row & 7) << 4);
            ah[i] = *(const short8*)((const char*)aH + off);
            al[i] = *(const short8*)((const char*)aL + off);
        }
        #pragma unroll
        for (int j = 0; j < 4; ++j) {
            int col = wn * 64 + j * 16 + lr;
            int off = (col * 128 + kk * 64 + kb * 16) ^ ((col & 7) << 4);
            short8 bh = *(const short8*)((const char*)bH + off);
            short8 bl = *(const short8*)((const char*)bL + off);
            #pragma unroll
            for (int i = 0; i < 2; ++i) {
                acc[i][j] = __builtin_amdgcn_mfma_f32_16x16x32_bf16(ah[i], bh, acc[i][j], 0, 0, 0);
                acc[i][j] = __builtin_amdgcn_mfma_f32_16x16x32_bf16(ah[i], bl, acc[i][j], 0, 0, 0);
                acc[i][j] = __builtin_amdgcn_mfma_f32_16x16x32_bf16(al[i], bh, acc[i][j], 0, 0, 0);
            }
        }
    }
}

// -- K1w: transpose + bf16-split Wv -> WvT in SWIZZLED TILED layout ----------
__global__ __launch_bounds__(256) void k_wvsplit(
    const float* __restrict__ Wv,
    unsigned short* __restrict__ WvTsh,
    unsigned short* __restrict__ WvTsl)
{
    __shared__ float tile[32][33];
    int k0 = blockIdx.x * 32, c0 = blockIdx.y * 32;
    int tx = threadIdx.x & 31, ty = threadIdx.x >> 5;
    #pragma unroll
    for (int i = 0; i < 4; ++i)
        tile[ty + i * 8][tx] = Wv[(size_t)(k0 + ty + i * 8) * CDIM + c0 + tx];
    __syncthreads();
    #pragma unroll
    for (int i = 0; i < 4; ++i) {
        int c = c0 + ty + i * 8, k = k0 + tx;
        float v = tile[tx][ty + i * 8];
        unsigned short hb = f2bf(v);
        int ct = c >> 7, rr = c & 127;
        size_t dst = ((size_t)(ct * 4 + (k >> 6)) * 128 + rr) * 64
                   + ((k & 63) ^ ((rr & 7) << 3));
        WvTsh[dst] = hb;
        WvTsl[dst] = f2bf(v - bf2f(hb));
    }
}

// ------- K1: value = input_flatten @ Wv + bv (bf16x3 MFMA), masked ----------
// 8 waves x 512, block tile 128x128, wave tile 32x64, BK=64, XOR-swizzled LDS.
// A: reg-prefetch + deferred conversion; B: global_load_lds from tiled WvT.
__global__ __launch_bounds__(512, 4) void k_value_mfma(
    const float* __restrict__ inp,            // (VTOT, 256)
    const unsigned char* __restrict__ mask,   // (VTOT)
    const unsigned short* __restrict__ WvTsh, // swizzled tiled (2x4x16KB)
    const unsigned short* __restrict__ WvTsl,
    const float* __restrict__ bv,             // (256)
    float* __restrict__ value)                // (VTOT, 256)
{
    __shared__ unsigned short aH[128 * 64], aL[128 * 64];   // 16KB x2
    __shared__ unsigned short bH[128 * 64], bL[128 * 64];   // 16KB x2
    const int row0 = blockIdx.y * 128;
    const int tid = threadIdx.x;
    const int lane = tid & 63;
    const int wid = tid >> 6;              // 0..7
    const int wm = wid >> 1, wn = wid & 1; // wave tile 32x64
    const int lr = lane & 15, kb = lane >> 4;

    f32x4 acc[2][4];
    #pragma unroll
    for (int i = 0; i < 2; ++i)
        #pragma unroll
        for (int j = 0; j < 4; ++j) acc[i][j] = f32x4{0.f, 0.f, 0.f, 0.f};

    // A staging slots: 1024 slots (128 rows x 8 k-octets), 2/thread
    int rc[2], ko[2], growA[2], soff[2];
    #pragma unroll
    for (int i2 = 0; i2 < 2; ++i2) {
        int slot = tid + i2 * 512;
        rc[i2] = slot >> 3; ko[i2] = slot & 7;
        int g = row0 + rc[i2];
        growA[i2] = (g < VTOT) ? g : (VTOT - 1);
        soff[i2] = (rc[i2] * 128 + ko[i2] * 16) ^ ((rc[i2] & 7) << 4);
    }

    // B gload bases (n-tile = blockIdx.x)
    const char* Bgh = (const char*)WvTsh + (size_t)blockIdx.x * 4 * 16384;
    const char* Bgl = (const char*)WvTsl + (size_t)blockIdx.x * 4 * 16384;
    const int lb = wid * 2048;             // wave-uniform LDS byte base
    const int gl = lb + (lane << 4);       // per-lane global byte offset

    // prologue: load A chunk 0, convert to hi/lo regs
    float4 fa0[2], fa1[2];
    short8 ha[2], la[2];
    #pragma unroll
    for (int i2 = 0; i2 < 2; ++i2) {
        const float* src = inp + (size_t)growA[i2] * CDIM + ko[i2] * 8;
        fa0[i2] = *(const float4*)src;
        fa1[i2] = *(const float4*)(src + 4);
    }
    #pragma unroll
    for (int i2 = 0; i2 < 2; ++i2) {
        float f[8] = {fa0[i2].x, fa0[i2].y, fa0[i2].z, fa0[i2].w,
                      fa1[i2].x, fa1[i2].y, fa1[i2].z, fa1[i2].w};
        #pragma unroll
        for (int e = 0; e < 8; ++e) {
            unsigned short hb = f2bf(f[e]);
            ha[i2][e] = (short)hb;
            la[i2][e] = (short)f2bf(f[e] - bf2f(hb));
        }
    }

    #pragma unroll
    for (int ch = 0; ch < 4; ++ch) {
        __syncthreads();   // previous chunk's LDS reads complete
        #pragma unroll
        for (int i2 = 0; i2 < 2; ++i2) {
            *(short8*)((char*)aH + soff[i2]) = ha[i2];
            *(short8*)((char*)aL + soff[i2]) = la[i2];
        }
        {
            const int cb = ch * 16384;
            gld16(Bgh + cb + gl,        (char*)bH + lb);
            gld16(Bgh + cb + gl + 1024, (char*)bH + lb + 1024);
            gld16(Bgl + cb + gl,        (char*)bL + lb);
            gld16(Bgl + cb + gl + 1024, (char*)bL + lb + 1024);
        }
        __syncthreads();   // drains vmcnt + lgkm -> LDS ready
        if (ch < 3) {      // next chunk's A loads fly during the MFMA phase
            const int k0n = (ch + 1) * 64;
            #pragma unroll
            for (int i2 = 0; i2 < 2; ++i2) {
                const float* src = inp + (size_t)growA[i2] * CDIM + k0n + ko[i2] * 8;
                fa0[i2] = *(const float4*)src;
                fa1[i2] = *(const float4*)(src + 4);
            }
        }
        mfma_32x64(aH, aL, bH, bL, wm, wn, lr, kb, acc);
        if (ch < 3) {      // convert under no barrier pressure
            #pragma unroll
            for (int i2 = 0; i2 < 2; ++i2) {
                float f[8] = {fa0[i2].x, fa0[i2].y, fa0[i2].z, fa0[i2].w,
                              fa1[i2].x, fa1[i2].y, fa1[i2].z, fa1[i2].w};
                #pragma unroll
                for (int e = 0; e < 8; ++e) {
                    unsigned short hb = f2bf(f[e]);
                    ha[i2][e] = (short)hb;
                    la[i2][e] = (short)f2bf(f[e] - bf2f(hb));
                }
            }
        }
    }

    // epilogue: bias + mask + store
    const int n0 = blockIdx.x * 128;
    #pragma unroll
    for (int j = 0; j < 4; ++j) {
        int c = n0 + wn * 64 + j * 16 + lr;
        float b = bv[c];
        #pragma unroll
        for (int i = 0; i < 2; ++i) {
            int q = row0 + wm * 32 + i * 16 + kb * 4;
            #pragma unroll
            for (int e = 0; e < 4; ++e) {
                int row = q + e;
                if (row < VTOT) {
                    float v = acc[i][j][e] + b;
                    if (mask[row]) v = 0.f;
                    value[(size_t)row * CDIM + c] = v;
                }
            }
        }
    }
}

// ----------- FALLBACK K1 (VALU version, if ws too small) ------------
__global__ __launch_bounds__(256) void k_value_proj(
    const float* __restrict__ inp,
    const unsigned char* __restrict__ mask,
    const float* __restrict__ Wv,
    const float* __restrict__ bv,
    float* __restrict__ value)
{
    const int ROWS = 16;
    __shared__ float a_s[ROWS][CDIM];
    const int total = VTOT;
    int row0 = blockIdx.x * ROWS;
    int tid = threadIdx.x;

    #pragma unroll
    for (int r = 0; r < ROWS; ++r) {
        int row = row0 + r;
        a_s[r][tid] = (row < total) ? inp[(size_t)row * CDIM + tid] : 0.f;
    }
    __syncthreads();

    float acc[ROWS];
    #pragma unroll
    for (int r = 0; r < ROWS; ++r) acc[r] = 0.f;

    for (int k = 0; k < CDIM; k += 4) {
        float w0 = Wv[(k + 0) * CDIM + tid];
        float w1 = Wv[(k + 1) * CDIM + tid];
        float w2 = Wv[(k + 2) * CDIM + tid];
        float w3 = Wv[(k + 3) * CDIM + tid];
        #pragma unroll
        for (int r = 0; r < ROWS; ++r) {
            float4 av = *(const float4*)&a_s[r][k];
            acc[r] = fmaf(av.x, w0, fmaf(av.y, w1, fmaf(av.z, w2, fmaf(av.w, w3, acc[r]))));
        }
    }

    float b = bv[tid];
    #pragma unroll
    for (int r = 0; r < ROWS; ++r) {
        int row = row0 + r;
        if (row < total) {
            float v = acc[r] + b;
            if (mask[row]) v = 0.f;
            value[(size_t)row * CDIM + tid] = v;
        }
    }
}

// -------- K2a: ROI-align (level 0) -> roi hi/lo in SWIZZLED TILED layout ----
// Pad blocks (q >= NQ_TOT) return immediately: their partials rows are never
// read by the epilogue, and stale/poison data is finite bf16 (no traps).
__global__ __launch_bounds__(256) void k_roi_split(
    const float* __restrict__ value,
    const float* __restrict__ refp,
    unsigned short* __restrict__ roiSh,   // (MPAD2*12544) swizzled tiled
    unsigned short* __restrict__ roiSl)
{
    int q = blockIdx.x;
    if (q >= NQ_TOT) return;
    int t = threadIdx.x;
    int g = t & 31;          // channel group (8 channels): k = i*256 + g*8
    int p8 = t >> 5;         // position slice 0..7
    const int mt = q >> 7, r = q & 127;
    const size_t tbase = (size_t)mt * KCH_TOT * 8192 + (size_t)r * 64;
    const int swz = ((r & 7) << 3);

    int n = q / LQ;
    const float* rp = refp + (size_t)q * NL * 4;   // level 0
    float cx = rp[0], cy = rp[1], w = rp[2], h = rp[3];
    float x1 = (cx - 0.5f * w) * W0 - 0.5f;
    float y1 = (cy - 0.5f * h) * H0 - 0.5f;
    float binw = w * W0 / ROI_;
    float binh = h * H0 / ROI_;
    const float* v0 = value + (size_t)n * LEN_IN * CDIM;

    for (int i = p8; i < 49; i += 8) {
        int rr = i / ROI_, c = i % ROI_;
        float sy = y1 + binh * (rr + 0.5f);
        float sx = x1 + binw * (c + 0.5f);
        float y0f = floorf(sy), x0f = floorf(sx);
        float wy1 = sy - y0f, wx1 = sx - x0f;
        int y0 = (int)y0f, x0 = (int)x0f;

        float acc[8];
        #pragma unroll
        for (int e = 0; e < 8; ++e) acc[e] = 0.f;

        #pragma unroll
        for (int dy = 0; dy <= 1; ++dy) {
            #pragma unroll
            for (int dx = 0; dx <= 1; ++dx) {
                int yy = y0 + dy, xx = x0 + dx;
                if (yy >= 0 && yy < H0 && xx >= 0 && xx < W0) {
                    float wgt = (dy ? wy1 : 1.f - wy1) * (dx ? wx1 : 1.f - wx1);
                    const float* src = v0 + ((size_t)(yy * W0 + xx)) * CDIM + g * 8;
                    float4 c0 = *(const float4*)src;
                    float4 c1 = *(const float4*)(src + 4);
                    acc[0] += wgt * c0.x; acc[1] += wgt * c0.y;
                    acc[2] += wgt * c0.z; acc[3] += wgt * c0.w;
                    acc[4] += wgt * c1.x; acc[5] += wgt * c1.y;
                    acc[6] += wgt * c1.z; acc[7] += wgt * c1.w;
                }
            }
        }

        short8 hv, lv;
        #pragma unroll
        for (int e = 0; e < 8; ++e) {
            unsigned short hb = f2bf(acc[e]);
            hv[e] = (short)hb;
            lv[e] = (short)f2bf(acc[e] - bf2f(hb));
        }
        int k = i * 256 + g * 8;
        size_t dst = tbase + (size_t)(k >> 6) * 8192 + ((k & 63) ^ swz);
        *(short8*)(roiSh + dst) = hv;
        *(short8*)(roiSl + dst) = lv;
    }
}

// ------ K2w: transpose + bf16-split [Wp|Ww] -> swizzled tiled (384x12544) ---
__global__ __launch_bounds__(256) void k_wsplit(
    const float* __restrict__ Wp,
    const float* __restrict__ Ww,
    unsigned short* __restrict__ WTsh,
    unsigned short* __restrict__ WTsl)
{
    __shared__ float tile[32][33];
    int k0 = blockIdx.x * 32, c0 = blockIdx.y * 32;
    int tx = threadIdx.x & 31, ty = threadIdx.x >> 5;

    #pragma unroll
    for (int i = 0; i < 4; ++i) {
        int k = k0 + ty + i * 8, c = c0 + tx;
        float v = (c < 256) ? Wp[(size_t)k * 256 + c] : Ww[(size_t)k * 128 + (c - 256)];
        tile[ty + i * 8][tx] = v;
    }
    __syncthreads();
    #pragma unroll
    for (int i = 0; i < 4; ++i) {
        int c = c0 + ty + i * 8, k = k0 + tx;
        float v = tile[tx][ty + i * 8];
        unsigned short hb = f2bf(v);
        float rem = v - bf2f(hb);
        int ct = c >> 7, rr = c & 127;
        size_t dst = ((size_t)(ct * KCH_TOT + (k >> 6)) * 128 + rr) * 64
                   + ((k & 63) ^ ((rr & 7) << 3));
        WTsh[dst] = hb;
        WTsl[dst] = f2bf(rem);
    }
}

// ------------- K2b: bf16x3 MFMA GEMM (MPAD2 x 384 x 12544), split-K ----------
__global__ __launch_bounds__(512, 4) void k_gemm_bf16x3(
    const unsigned short* __restrict__ roiSh,
    const unsigned short* __restrict__ roiSl,
    const unsigned short* __restrict__ WTsh,
    const unsigned short* __restrict__ WTsl,
    float* __restrict__ partials,      // (nseg, MPAD2, 384)
    int gch)
{
    __shared__ unsigned short aH[128 * 64], aL[128 * 64];
    __shared__ unsigned short bH[128 * 64], bL[128 * 64];

    const int nwg = gridDim.x;
    const int q8 = nwg >> 3, r8 = nwg & 7;
    const int xcd = blockIdx.x & 7, pos = blockIdx.x >> 3;
    const int start = (xcd < r8) ? xcd * (q8 + 1) : r8 * (q8 + 1) + (xcd - r8) * q8;
    const int lin = start + pos;
    const int mt = lin % MT_N;
    const int t2 = lin / MT_N;
    const int nt = t2 % NT_N;
    const int seg = t2 / NT_N;

    const int q0 = mt * 128, c0 = nt * 128;
    const int tid = threadIdx.x;
    const int lane = tid & 63;
    const int wid = tid >> 6;
    const int wm = wid >> 1, wn = wid & 1;
    const int lr = lane & 15, kb = lane >> 4;

    f32x4 acc[2][4];
    #pragma unroll
    for (int i = 0; i < 2; ++i)
        #pragma unroll
        for (int j = 0; j < 4; ++j) acc[i][j] = f32x4{0.f, 0.f, 0.f, 0.f};

    const char* Agh = (const char*)roiSh + (size_t)mt * KCH_TOT * 16384;
    const char* Agl = (const char*)roiSl + (size_t)mt * KCH_TOT * 16384;
    const char* Bgh = (const char*)WTsh + (size_t)nt * KCH_TOT * 16384;
    const char* Bgl = (const char*)WTsl + (size_t)nt * KCH_TOT * 16384;
    const int lb = wid * 2048;             // wave-uniform LDS byte base
    const int gl = lb + (lane << 4);       // per-lane global byte offset

    const int ch0 = seg * gch;

    for (int ch = 0; ch < gch; ++ch) {
        const size_t cb = (size_t)(ch0 + ch) * 16384;
        __syncthreads();   // previous chunk's LDS reads complete
        gld16(Agh + cb + gl,        (char*)aH + lb);
        gld16(Agh + cb + gl + 1024, (char*)aH + lb + 1024);
        gld16(Agl + cb + gl,        (char*)aL + lb);
        gld16(Agl + cb + gl + 1024, (char*)aL + lb + 1024);
        gld16(Bgh + cb + gl,        (char*)bH + lb);
        gld16(Bgh + cb + gl + 1024, (char*)bH + lb + 1024);
        gld16(Bgl + cb + gl,        (char*)bL + lb);
        gld16(Bgl + cb + gl + 1024, (char*)bL + lb + 1024);
        __syncthreads();   // drains vmcnt -> LDS ready
        mfma_32x64(aH, aL, bH, bL, wm, wn, lr, kb, acc);
    }

    #pragma unroll
    for (int i = 0; i < 2; ++i)
        #pragma unroll
        for (int j = 0; j < 4; ++j) {
            int q = q0 + wm * 32 + i * 16 + kb * 4;
            int c = c0 + wn * 64 + j * 16 + lr;
            #pragma unroll
            for (int e = 0; e < 4; ++e)
                partials[((size_t)seg * MPAD2 + q + e) * NDIM + c] = acc[i][j][e];
        }
}

// -- K3': FUSED epilogue + sampling. One block per query (384 threads). ------
// Phase 1: reduce partials + bias -> pr (tanh, LDS) / logits; phase 2: 16-wide
// softmax -> attn (LDS); phase 3: deformable sampling reading pr/attn from LDS.
__global__ __launch_bounds__(384) void k_sample_ep(
    const float* __restrict__ partials,   // (nseg, MPAD2, 384)
    const float* __restrict__ bp, const float* __restrict__ bw,
    const float* __restrict__ refp,
    const float* __restrict__ value,
    float* __restrict__ out_attn,         // (1200, 256)
    int nseg)
{
    __shared__ float pr_s[256];
    __shared__ float attn_s[128];
    __shared__ float logit_s[128];
    const int q = blockIdx.x;
    const int t = threadIdx.x;

    // phase 1: split-K reduce + bias
    float s = 0.f;
    for (int g = 0; g < nseg; ++g)
        s += partials[((size_t)g * MPAD2 + q) * NDIM + t];
    if (t < 256) {
        pr_s[t] = tanhf(s + bp[t]);
    } else {
        logit_s[t - 256] = s + bw[t - 256];
    }
    __syncthreads();

    // phase 2: softmax over groups of 16 (per head x level*point)
    if (t < 128) {
        float v = logit_s[t];
        float m = v;
        #pragma unroll
        for (int off = 8; off >= 1; off >>= 1)
            m = fmaxf(m, __shfl_xor(m, off, 16));
        float e = expf(v - m);
        float sum = e;
        #pragma unroll
        for (int off = 8; off >= 1; off >>= 1)
            sum += __shfl_xor(sum, off, 16);
        attn_s[t] = e / sum;
    }
    __syncthreads();

    // phase 3: multi-scale deformable sampling (threads 0..255)
    if (t < 256) {
        int n = q / LQ;
        int h = t >> 5, dh = t & 31;
        float acc = 0.f;
        for (int l = 0; l < NL; ++l) {
            const float* rp = refp + ((size_t)q * NL + l) * 4;
            float cx = rp[0], cy = rp[1], rw = rp[2], rh = rp[3];
            int Hl = d_HL[l], Wl = d_WL[l], st = d_ST[l];
            const float* vl = value + ((size_t)n * LEN_IN + st) * CDIM;

            #pragma unroll
            for (int p = 0; p < NP; ++p) {
                float prx = pr_s[h * 32 + l * 8 + p * 2 + 0];
                float pry = pr_s[h * 32 + l * 8 + p * 2 + 1];
                float a   = attn_s[h * 16 + l * 4 + p];
                float px = (cx + prx * rw * 0.5f) * Wl - 0.5f;
                float py = (cy + pry * rh * 0.5f) * Hl - 0.5f;
                float x0f = floorf(px), y0f = floorf(py);
                float wx1 = px - x0f, wy1 = py - y0f;
                int x0 = (int)x0f, y0 = (int)y0f;
                float sv = 0.f;
                #pragma unroll
                for (int dy = 0; dy <= 1; ++dy)
                    #pragma unroll
                    for (int dx = 0; dx <= 1; ++dx) {
                        int yy = y0 + dy, xx = x0 + dx;
                        if (yy >= 0 && yy < Hl && xx >= 0 && xx < Wl) {
                            float wgt = (dy ? wy1 : 1.f - wy1) * (dx ? wx1 : 1.f - wx1);
                            sv += wgt * vl[((size_t)(yy * Wl + xx)) * CDIM + h * 32 + dh];
                        }
                    }
                acc += a * sv;
            }
        }
        out_attn[(size_t)q * CDIM + t] = acc;
    }
}

// ------- FALLBACK K2 (round-1 fused kernel) used only if ws too small -------
__global__ __launch_bounds__(384) void k_roi_gemm(
    const float* __restrict__ value,
    const float* __restrict__ refp,
    const float* __restrict__ Wp,
    const float* __restrict__ bp,
    const float* __restrict__ Ww,
    const float* __restrict__ bw,
    float* __restrict__ pr_out,
    float* __restrict__ attn_out)
{
    __shared__ float roi_s[QPB][ROI_DIM];
    __shared__ float logit_s[QPB][128];

    int tid = threadIdx.x;
    int nq0 = blockIdx.x * QPB;

    for (int qi = 0; qi < QPB; ++qi) {
        int nq = nq0 + qi;
        int n = nq / LQ;
        const float* rp = refp + (size_t)nq * NL * 4;
        float cx = rp[0], cy = rp[1], w = rp[2], h = rp[3];
        float x1 = (cx - 0.5f * w) * W0 - 0.5f;
        float y1 = (cy - 0.5f * h) * H0 - 0.5f;
        float binw = w * W0 / ROI_;
        float binh = h * H0 / ROI_;
        const float* v0 = value + (size_t)n * LEN_IN * CDIM;

        for (int e = tid; e < ROI_DIM; e += 384) {
            int p = e >> 8;
            int ch = e & 255;
            int r = p / ROI_, c = p % ROI_;
            float sy = y1 + binh * (r + 0.5f);
            float sx = x1 + binw * (c + 0.5f);
            float y0f = floorf(sy), x0f = floorf(sx);
            float wy1 = sy - y0f, wx1 = sx - x0f;
            int y0 = (int)y0f, x0 = (int)x0f;
            float acc = 0.f;
            #pragma unroll
            for (int dy = 0; dy <= 1; ++dy)
                #pragma unroll
                for (int dx = 0; dx <= 1; ++dx) {
                    int yy = y0 + dy, xx = x0 + dx;
                    if (yy >= 0 && yy < H0 && xx >= 0 && xx < W0) {
                        float wgt = (dy ? wy1 : 1.f - wy1) * (dx ? wx1 : 1.f - wx1);
                        acc += wgt * v0[((size_t)(yy * W0 + xx)) * CDIM + ch];
                    }
                }
            roi_s[qi][e] = acc;
        }
    }
    __syncthreads();

    int col = tid;
    const float* Wsel;
    int stride;
    float bias;
    if (col < 256) { Wsel = Wp + col;         stride = 256; bias = bp[col]; }
    else           { Wsel = Ww + (col - 256); stride = 128; bias = bw[col - 256]; }

    float acc0 = 0.f, acc1 = 0.f, acc2 = 0.f;
    const float* wptr = Wsel;
    #pragma unroll 8
    for (int k = 0; k < ROI_DIM; ++k) {
        float wv = *wptr; wptr += stride;
        acc0 += roi_s[0][k] * wv;
        acc1 += roi_s[1][k] * wv;
        acc2 += roi_s[2][k] * wv;
    }
    acc0 += bias; acc1 += bias; acc2 += bias;

    if (col < 256) {
        pr_out[(size_t)(nq0 + 0) * 256 + col] = tanhf(acc0);
        pr_out[(size_t)(nq0 + 1) * 256 + col] = tanhf(acc1);
        pr_out[(size_t)(nq0 + 2) * 256 + col] = tanhf(acc2);
    } else {
        int j = col - 256;
        logit_s[0][j] = acc0;
        logit_s[1][j] = acc1;
        logit_s[2][j] = acc2;
    }
    __syncthreads();

    {
        int i = tid & 15;
        int g = tid >> 4;
        int qi = g >> 3, h = g & 7;
        float v = logit_s[qi][h * 16 + i];
        float m = v;
        #pragma unroll
        for (int off = 8; off >= 1; off >>= 1)
            m = fmaxf(m, __shfl_xor(m, off, 16));
        float e = expf(v - m);
        float s = e;
        #pragma unroll
        for (int off = 8; off >= 1; off >>= 1)
            s += __shfl_xor(s, off, 16);
        attn_out[(size_t)(nq0 + qi) * 128 + h * 16 + i] = e / s;
    }
}

// --------- FALLBACK K3: deformable sampling (global pr/attn) ----------
__global__ __launch_bounds__(256) void k_sample(
    const float* __restrict__ value,
    const float* __restrict__ refp,
    const float* __restrict__ pr,
    const float* __restrict__ attn,
    float* __restrict__ out_attn)
{
    int nq = blockIdx.x;
    int n = nq / LQ;
    int tid = threadIdx.x;
    int h = tid >> 5, dh = tid & 31;

    float acc = 0.f;
    for (int l = 0; l < NL; ++l) {
        const float* rp = refp + ((size_t)nq * NL + l) * 4;
        float cx = rp[0], cy = rp[1], rw = rp[2], rh = rp[3];
        int Hl = d_HL[l], Wl = d_WL[l], s = d_ST[l];
        const float* vl = value + ((size_t)n * LEN_IN + s) * CDIM;

        #pragma unroll
        for (int p = 0; p < NP; ++p) {
            float prx = pr[(size_t)nq * 256 + h * 32 + l * 8 + p * 2 + 0];
            float pry = pr[(size_t)nq * 256 + h * 32 + l * 8 + p * 2 + 1];
            float a   = attn[(size_t)nq * 128 + h * 16 + l * 4 + p];
            float px = (cx + prx * rw * 0.5f) * Wl - 0.5f;
            float py = (cy + pry * rh * 0.5f) * Hl - 0.5f;
            float x0f = floorf(px), y0f = floorf(py);
            float wx1 = px - x0f, wy1 = py - y0f;
            int x0 = (int)x0f, y0 = (int)y0f;
            float sv = 0.f;
            #pragma unroll
            for (int dy = 0; dy <= 1; ++dy)
                #pragma unroll
                for (int dx = 0; dx <= 1; ++dx) {
                    int yy = y0 + dy, xx = x0 + dx;
                    if (yy >= 0 && yy < Hl && xx >= 0 && xx < Wl) {
                        float wgt = (dy ? wy1 : 1.f - wy1) * (dx ? wx1 : 1.f - wx1);
                        sv += wgt * vl[((size_t)(yy * Wl + xx)) * CDIM + h * 32 + dh];
                    }
                }
            acc += a * sv;
        }
    }
    out_attn[(size_t)nq * CDIM + tid] = acc;
}

// ---------------- K4: out = out_attn @ Wo + bo ----------------
__global__ __launch_bounds__(256) void k_out_proj(
    const float* __restrict__ x,
    const float* __restrict__ Wo,
    const float* __restrict__ bo,
    float* __restrict__ out)
{
    const int ROWS = 8;
    __shared__ float a_s[ROWS][CDIM];
    int row0 = blockIdx.x * ROWS;
    int tid = threadIdx.x;

    #pragma unroll
    for (int r = 0; r < ROWS; ++r)
        a_s[r][tid] = x[(size_t)(row0 + r) * CDIM + tid];
    __syncthreads();

    float acc[ROWS];
    #pragma unroll
    for (int r = 0; r < ROWS; ++r) acc[r] = 0.f;

    for (int k = 0; k < CDIM; k += 4) {
        float w0 = Wo[(k + 0) * CDIM + tid];
        float w1 = Wo[(k + 1) * CDIM + tid];
        float w2 = Wo[(k + 2) * CDIM + tid];
        float w3 = Wo[(k + 3) * CDIM + tid];
        #pragma unroll
        for (int r = 0; r < ROWS; ++r) {
            float4 av = *(const float4*)&a_s[r][k];
            acc[r] = fmaf(av.x, w0, fmaf(av.y, w1, fmaf(av.z, w2, fmaf(av.w, w3, acc[r]))));
        }
    }
    float b = bo[tid];
    #pragma unroll
    for (int r = 0; r < ROWS; ++r)
        out[(size_t)(row0 + r) * CDIM + tid] = acc[r] + b;
}

extern "C" void kernel_launch(void* const* d_in, const int* in_sizes, int n_in,
                              void* d_out, int out_size, void* d_ws, size_t ws_size,
                              hipStream_t stream) {
    const float* refp = (const float*)d_in[1];
    const float* inp  = (const float*)d_in[2];
    const unsigned char* mask = (const unsigned char*)d_in[5];
    const float* Wv = (const float*)d_in[6];
    const float* bv = (const float*)d_in[7];
    const float* Wp = (const float*)d_in[8];
    const float* bp = (const float*)d_in[9];
    const float* Ww = (const float*)d_in[10];
    const float* bw = (const float*)d_in[11];
    const float* Wo = (const float*)d_in[12];
    const float* bo = (const float*)d_in[13];
    float* out = (float*)d_out;

    // workspace layout (fixed part)
    char* ws = (char*)d_ws;
    constexpr size_t VALUE_BYTES = (size_t)VTOT * CDIM * 4;               // 81,702,912
    constexpr size_t ROI_BYTES   = (size_t)MPAD2 * ROI_DIM * 2;           // 32,112,640
    constexpr size_t WT_BYTES    = (size_t)NDIM * ROI_DIM * 2;            //  9,633,792
    constexpr size_t WVT_BYTES   = (size_t)CDIM * CDIM * 2;               //    131,072
    constexpr size_t SEG_BYTES   = (size_t)MPAD2 * NDIM * 4;              //  1,966,080
    constexpr size_t PR_BYTES    = (size_t)NQ_TOT * 256 * 4;
    constexpr size_t ATTN_BYTES  = (size_t)NQ_TOT * 128 * 4;
    constexpr size_t OA_BYTES    = (size_t)NQ_TOT * 256 * 4;

    size_t off = 0;
    float* value = (float*)(ws + off);                  off += VALUE_BYTES;
    unsigned short* roiSh = (unsigned short*)(ws + off); off += ROI_BYTES;
    unsigned short* roiSl = (unsigned short*)(ws + off); off += ROI_BYTES;
    unsigned short* WTsh  = (unsigned short*)(ws + off); off += WT_BYTES;
    unsigned short* WTsl  = (unsigned short*)(ws + off); off += WT_BYTES;
    unsigned short* WvTsh = (unsigned short*)(ws + off); off += WVT_BYTES;
    unsigned short* WvTsl = (unsigned short*)(ws + off); off += WVT_BYTES;
    const size_t fixed_end = off;
    const size_t tail = OA_BYTES;

    // choose split-K depth by workspace headroom (nseg must divide 196)
    int nseg = 0;
    if (ws_size >= fixed_end + 14 * SEG_BYTES + tail)      nseg = 14;
    else if (ws_size >= fixed_end + 7 * SEG_BYTES + tail)  nseg = 7;

    if (nseg > 0) {
        float* partials = (float*)(ws + fixed_end);
        size_t o2 = fixed_end + (size_t)nseg * SEG_BYTES;
        float* out_attn = (float*)(ws + o2);

        // K1: Wv split (swizzled tiled) + MFMA value projection (B gload_lds)
        k_wvsplit<<<dim3(CDIM / 32, CDIM / 32), 256, 0, stream>>>(Wv, WvTsh, WvTsl);
        k_value_mfma<<<dim3(2, VMT), 512, 0, stream>>>(inp, mask, WvTsh, WvTsl, bv, value);
        // K2a: ROI align -> bf16 hi/lo, swizzled tiled layout
        k_roi_split<<<MPAD2, 256, 0, stream>>>(value, refp, roiSh, roiSl);
        // K2w: W transpose + split, swizzled tiled layout
        k_wsplit<<<dim3(ROI_DIM / 32, NDIM / 32), 256, 0, stream>>>(Wp, Ww, WTsh, WTsl);
        // K2b: bf16x3 MFMA GEMM, split-K, XCD swizzle, global_load_lds staging
        k_gemm_bf16x3<<<MT_N * NT_N * nseg, 512, 0, stream>>>(
            roiSh, roiSl, WTsh, WTsl, partials, KCH_TOT / nseg);
        // K3': fused epilogue (reduce+tanh+softmax) + deformable sampling
        k_sample_ep<<<NQ_TOT, 384, 0, stream>>>(
            partials, bp, bw, refp, value, out_attn, nseg);
        // K4
        k_out_proj<<<NQ_TOT / 8, 256, 0, stream>>>(out_attn, Wo, bo, out);
    } else {
        // fallback: round-1/2 path (small ws)
        float* pr       = (float*)(ws + VALUE_BYTES);
        float* attn     = (float*)(ws + VALUE_BYTES + PR_BYTES);
        float* out_attn = (float*)(ws + VALUE_BYTES + PR_BYTES + ATTN_BYTES);
        k_value_proj<<<(VTOT + 15) / 16, 256, 0, stream>>>(inp, mask, Wv, bv, value);
        k_roi_gemm<<<NQ_TOT / QPB, 384, 0, stream>>>(value, refp, Wp, bp, Ww, bw, pr, attn);
        k_sample<<<NQ_TOT, 256, 0, stream>>>(value, refp, pr, attn, out_attn);
        k_out_proj<<<NQ_TOT / 8, 256, 0, stream>>>(out_attn, Wo, bo, out);
    }
}

// Round 16
// 213.756 us; speedup vs baseline: 1.0132x; 1.0132x over previous
//
#include <hip/hip_runtime.h>
#include <hip/hip_bf16.h>
#include <math.h>

// Problem constants (fixed by setup_inputs)
#define NB 4
#define LQ 300
#define CDIM 256
#define NH 8
#define DH 32
#define NL 4
#define NP 4
#define ROI_ 7
#define LEN_IN 19947
#define H0 100
#define W0 150
#define ROI_DIM (ROI_*ROI_*CDIM)   // 12544
#define NQ_TOT (NB*LQ)             // 1200
#define QPB 3                      // queries per block in fallback K2

// K2b GEMM config
#define MPAD2 1280                 // 10 * 128
#define NDIM 384
#define KCH_TOT 196                // 12544 / 64
#define MT_N 10                    // MPAD2/128
#define NT_N 3                     // NDIM/128

// K1 GEMM config
#define VTOT (NB*LEN_IN)           // 79788
#define VMT  624                   // ceil(79788/128)

__device__ __constant__ int d_HL[4] = {100, 50, 25, 13};
__device__ __constant__ int d_WL[4] = {150, 75, 38, 19};
__device__ __constant__ int d_ST[4] = {0, 15000, 18750, 19700};

typedef __attribute__((ext_vector_type(8))) short short8;
typedef __attribute__((ext_vector_type(4))) float f32x4;

__device__ __forceinline__ unsigned short f2bf(float f) {
    unsigned int u = __float_as_uint(f);
    unsigned int r = (u + 0x7fffu + ((u >> 16) & 1u)) >> 16;
    return (unsigned short)r;
}
__device__ __forceinline__ float bf2f(unsigned short s) {
    return __uint_as_float(((unsigned int)s) << 16);
}

// HBM -> LDS direct copy, 16B per lane (global_load_lds_dwordx4).
__device__ __forceinline__ void gld16(const void* g, void* l) {
    __builtin_amdgcn_global_load_lds(
        (const __attribute__((address_space(1))) unsigned int*)g,
        (__attribute__((address_space(3))) unsigned int*)l, 16, 0, 0);
}

// 8-wave inner loop: one 128x128 block-tile K-step (K=64), wave tile 32x64,
// hi/lo bf16 in LDS (XOR-swizzled), 3-product accumulate. acc = 32 VGPRs.
__device__ __forceinline__ void mfma_32x64(
    const unsigned short* aH, const unsigned short* aL,
    const unsigned short* bH, const unsigned short* bL,
    int wm, int wn, int lr, int kb, f32x4 acc[2][4])
{
    #pragma unroll
    for (int kk = 0; kk < 2; ++kk) {
        short8 ah[2], al[2];
        #pragma unroll
        for (int i = 0; i < 2; ++i) {
            int row = wm * 32 + i * 16 + lr;
            int off = (row * 128 + kk * 64 + kb * 16) ^ ((row & 7) << 4);
            ah[i] = *(const short8*)((const char*)aH + off);
            al[i] = *(const short8*)((const char*)aL + off);
        }
        #pragma unroll
        for (int j = 0; j < 4; ++j) {
            int col = wn * 64 + j * 16 + lr;
            int off = (col * 128 + kk * 64 + kb * 16) ^ ((col & 7) << 4);
            short8 bh = *(const short8*)((const char*)bH + off);
            short8 bl = *(const short8*)((const char*)bL + off);
            #pragma unroll
            for (int i = 0; i < 2; ++i) {
                acc[i][j] = __builtin_amdgcn_mfma_f32_16x16x32_bf16(ah[i], bh, acc[i][j], 0, 0, 0);
                acc[i][j] = __builtin_amdgcn_mfma_f32_16x16x32_bf16(ah[i], bl, acc[i][j], 0, 0, 0);
                acc[i][j] = __builtin_amdgcn_mfma_f32_16x16x32_bf16(al[i], bh, acc[i][j], 0, 0, 0);
            }
        }
    }
}

// -- K1w: transpose + bf16-split Wv -> WvT in SWIZZLED TILED layout ----------
__global__ __launch_bounds__(256) void k_wvsplit(
    const float* __restrict__ Wv,
    unsigned short* __restrict__ WvTsh,
    unsigned short* __restrict__ WvTsl)
{
    __shared__ float tile[32][33];
    int k0 = blockIdx.x * 32, c0 = blockIdx.y * 32;
    int tx = threadIdx.x & 31, ty = threadIdx.x >> 5;
    #pragma unroll
    for (int i = 0; i < 4; ++i)
        tile[ty + i * 8][tx] = Wv[(size_t)(k0 + ty + i * 8) * CDIM + c0 + tx];
    __syncthreads();
    #pragma unroll
    for (int i = 0; i < 4; ++i) {
        int c = c0 + ty + i * 8, k = k0 + tx;
        float v = tile[tx][ty + i * 8];
        unsigned short hb = f2bf(v);
        int ct = c >> 7, rr = c & 127;
        size_t dst = ((size_t)(ct * 4 + (k >> 6)) * 128 + rr) * 64
                   + ((k & 63) ^ ((rr & 7) << 3));
        WvTsh[dst] = hb;
        WvTsl[dst] = f2bf(v - bf2f(hb));
    }
}

// ------- K1: value = input_flatten @ Wv + bv (bf16x3 MFMA), masked ----------
// 8 waves x 512, block tile 128x128, wave tile 32x64, BK=64, XOR-swizzled LDS.
// A: reg-prefetch + deferred conversion; B: global_load_lds from tiled WvT.
__global__ __launch_bounds__(512, 4) void k_value_mfma(
    const float* __restrict__ inp,            // (VTOT, 256)
    const unsigned char* __restrict__ mask,   // (VTOT)
    const unsigned short* __restrict__ WvTsh, // swizzled tiled (2x4x16KB)
    const unsigned short* __restrict__ WvTsl,
    const float* __restrict__ bv,             // (256)
    float* __restrict__ value)                // (VTOT, 256)
{
    __shared__ unsigned short aH[128 * 64], aL[128 * 64];   // 16KB x2
    __shared__ unsigned short bH[128 * 64], bL[128 * 64];   // 16KB x2
    const int row0 = blockIdx.y * 128;
    const int tid = threadIdx.x;
    const int lane = tid & 63;
    const int wid = tid >> 6;              // 0..7
    const int wm = wid >> 1, wn = wid & 1; // wave tile 32x64
    const int lr = lane & 15, kb = lane >> 4;

    f32x4 acc[2][4];
    #pragma unroll
    for (int i = 0; i < 2; ++i)
        #pragma unroll
        for (int j = 0; j < 4; ++j) acc[i][j] = f32x4{0.f, 0.f, 0.f, 0.f};

    // A staging slots: 1024 slots (128 rows x 8 k-octets), 2/thread
    int rc[2], ko[2], growA[2], soff[2];
    #pragma unroll
    for (int i2 = 0; i2 < 2; ++i2) {
        int slot = tid + i2 * 512;
        rc[i2] = slot >> 3; ko[i2] = slot & 7;
        int g = row0 + rc[i2];
        growA[i2] = (g < VTOT) ? g : (VTOT - 1);
        soff[i2] = (rc[i2] * 128 + ko[i2] * 16) ^ ((rc[i2] & 7) << 4);
    }

    // B gload bases (n-tile = blockIdx.x)
    const char* Bgh = (const char*)WvTsh + (size_t)blockIdx.x * 4 * 16384;
    const char* Bgl = (const char*)WvTsl + (size_t)blockIdx.x * 4 * 16384;
    const int lb = wid * 2048;             // wave-uniform LDS byte base
    const int gl = lb + (lane << 4);       // per-lane global byte offset

    // prologue: load A chunk 0, convert to hi/lo regs
    float4 fa0[2], fa1[2];
    short8 ha[2], la[2];
    #pragma unroll
    for (int i2 = 0; i2 < 2; ++i2) {
        const float* src = inp + (size_t)growA[i2] * CDIM + ko[i2] * 8;
        fa0[i2] = *(const float4*)src;
        fa1[i2] = *(const float4*)(src + 4);
    }
    #pragma unroll
    for (int i2 = 0; i2 < 2; ++i2) {
        float f[8] = {fa0[i2].x, fa0[i2].y, fa0[i2].z, fa0[i2].w,
                      fa1[i2].x, fa1[i2].y, fa1[i2].z, fa1[i2].w};
        #pragma unroll
        for (int e = 0; e < 8; ++e) {
            unsigned short hb = f2bf(f[e]);
            ha[i2][e] = (short)hb;
            la[i2][e] = (short)f2bf(f[e] - bf2f(hb));
        }
    }

    #pragma unroll
    for (int ch = 0; ch < 4; ++ch) {
        __syncthreads();   // previous chunk's LDS reads complete
        #pragma unroll
        for (int i2 = 0; i2 < 2; ++i2) {
            *(short8*)((char*)aH + soff[i2]) = ha[i2];
            *(short8*)((char*)aL + soff[i2]) = la[i2];
        }
        {
            const int cb = ch * 16384;
            gld16(Bgh + cb + gl,        (char*)bH + lb);
            gld16(Bgh + cb + gl + 1024, (char*)bH + lb + 1024);
            gld16(Bgl + cb + gl,        (char*)bL + lb);
            gld16(Bgl + cb + gl + 1024, (char*)bL + lb + 1024);
        }
        __syncthreads();   // drains vmcnt + lgkm -> LDS ready
        if (ch < 3) {      // next chunk's A loads fly during the MFMA phase
            const int k0n = (ch + 1) * 64;
            #pragma unroll
            for (int i2 = 0; i2 < 2; ++i2) {
                const float* src = inp + (size_t)growA[i2] * CDIM + k0n + ko[i2] * 8;
                fa0[i2] = *(const float4*)src;
                fa1[i2] = *(const float4*)(src + 4);
            }
        }
        mfma_32x64(aH, aL, bH, bL, wm, wn, lr, kb, acc);
        if (ch < 3) {      // convert under no barrier pressure
            #pragma unroll
            for (int i2 = 0; i2 < 2; ++i2) {
                float f[8] = {fa0[i2].x, fa0[i2].y, fa0[i2].z, fa0[i2].w,
                              fa1[i2].x, fa1[i2].y, fa1[i2].z, fa1[i2].w};
                #pragma unroll
                for (int e = 0; e < 8; ++e) {
                    unsigned short hb = f2bf(f[e]);
                    ha[i2][e] = (short)hb;
                    la[i2][e] = (short)f2bf(f[e] - bf2f(hb));
                }
            }
        }
    }

    // epilogue: bias + mask + store
    const int n0 = blockIdx.x * 128;
    #pragma unroll
    for (int j = 0; j < 4; ++j) {
        int c = n0 + wn * 64 + j * 16 + lr;
        float b = bv[c];
        #pragma unroll
        for (int i = 0; i < 2; ++i) {
            int q = row0 + wm * 32 + i * 16 + kb * 4;
            #pragma unroll
            for (int e = 0; e < 4; ++e) {
                int row = q + e;
                if (row < VTOT) {
                    float v = acc[i][j][e] + b;
                    if (mask[row]) v = 0.f;
                    value[(size_t)row * CDIM + c] = v;
                }
            }
        }
    }
}

// ----------- FALLBACK K1 (VALU version, if ws too small) ------------
__global__ __launch_bounds__(256) void k_value_proj(
    const float* __restrict__ inp,
    const unsigned char* __restrict__ mask,
    const float* __restrict__ Wv,
    const float* __restrict__ bv,
    float* __restrict__ value)
{
    const int ROWS = 16;
    __shared__ float a_s[ROWS][CDIM];
    const int total = VTOT;
    int row0 = blockIdx.x * ROWS;
    int tid = threadIdx.x;

    #pragma unroll
    for (int r = 0; r < ROWS; ++r) {
        int row = row0 + r;
        a_s[r][tid] = (row < total) ? inp[(size_t)row * CDIM + tid] : 0.f;
    }
    __syncthreads();

    float acc[ROWS];
    #pragma unroll
    for (int r = 0; r < ROWS; ++r) acc[r] = 0.f;

    for (int k = 0; k < CDIM; k += 4) {
        float w0 = Wv[(k + 0) * CDIM + tid];
        float w1 = Wv[(k + 1) * CDIM + tid];
        float w2 = Wv[(k + 2) * CDIM + tid];
        float w3 = Wv[(k + 3) * CDIM + tid];
        #pragma unroll
        for (int r = 0; r < ROWS; ++r) {
            float4 av = *(const float4*)&a_s[r][k];
            acc[r] = fmaf(av.x, w0, fmaf(av.y, w1, fmaf(av.z, w2, fmaf(av.w, w3, acc[r]))));
        }
    }

    float b = bv[tid];
    #pragma unroll
    for (int r = 0; r < ROWS; ++r) {
        int row = row0 + r;
        if (row < total) {
            float v = acc[r] + b;
            if (mask[row]) v = 0.f;
            value[(size_t)row * CDIM + tid] = v;
        }
    }
}

// -------- K2a: ROI-align (level 0) -> roi hi/lo in SWIZZLED TILED layout ----
// Launched with exactly NQ_TOT blocks; pad rows of the GEMM read stale finite
// bf16 and their outputs (rows >= 1200) are never consumed.
__global__ __launch_bounds__(256) void k_roi_split(
    const float* __restrict__ value,
    const float* __restrict__ refp,
    unsigned short* __restrict__ roiSh,   // (MPAD2*12544) swizzled tiled
    unsigned short* __restrict__ roiSl)
{
    int q = blockIdx.x;
    int t = threadIdx.x;
    int g = t & 31;          // channel group (8 channels): k = i*256 + g*8
    int p8 = t >> 5;         // position slice 0..7
    const int mt = q >> 7, r = q & 127;
    const size_t tbase = (size_t)mt * KCH_TOT * 8192 + (size_t)r * 64;
    const int swz = ((r & 7) << 3);

    int n = q / LQ;
    const float* rp = refp + (size_t)q * NL * 4;   // level 0
    float cx = rp[0], cy = rp[1], w = rp[2], h = rp[3];
    float x1 = (cx - 0.5f * w) * W0 - 0.5f;
    float y1 = (cy - 0.5f * h) * H0 - 0.5f;
    float binw = w * W0 / ROI_;
    float binh = h * H0 / ROI_;
    const float* v0 = value + (size_t)n * LEN_IN * CDIM;

    for (int i = p8; i < 49; i += 8) {
        int rr = i / ROI_, c = i % ROI_;
        float sy = y1 + binh * (rr + 0.5f);
        float sx = x1 + binw * (c + 0.5f);
        float y0f = floorf(sy), x0f = floorf(sx);
        float wy1 = sy - y0f, wx1 = sx - x0f;
        int y0 = (int)y0f, x0 = (int)x0f;

        float acc[8];
        #pragma unroll
        for (int e = 0; e < 8; ++e) acc[e] = 0.f;

        #pragma unroll
        for (int dy = 0; dy <= 1; ++dy) {
            #pragma unroll
            for (int dx = 0; dx <= 1; ++dx) {
                int yy = y0 + dy, xx = x0 + dx;
                if (yy >= 0 && yy < H0 && xx >= 0 && xx < W0) {
                    float wgt = (dy ? wy1 : 1.f - wy1) * (dx ? wx1 : 1.f - wx1);
                    const float* src = v0 + ((size_t)(yy * W0 + xx)) * CDIM + g * 8;
                    float4 c0 = *(const float4*)src;
                    float4 c1 = *(const float4*)(src + 4);
                    acc[0] += wgt * c0.x; acc[1] += wgt * c0.y;
                    acc[2] += wgt * c0.z; acc[3] += wgt * c0.w;
                    acc[4] += wgt * c1.x; acc[5] += wgt * c1.y;
                    acc[6] += wgt * c1.z; acc[7] += wgt * c1.w;
                }
            }
        }

        short8 hv, lv;
        #pragma unroll
        for (int e = 0; e < 8; ++e) {
            unsigned short hb = f2bf(acc[e]);
            hv[e] = (short)hb;
            lv[e] = (short)f2bf(acc[e] - bf2f(hb));
        }
        int k = i * 256 + g * 8;
        size_t dst = tbase + (size_t)(k >> 6) * 8192 + ((k & 63) ^ swz);
        *(short8*)(roiSh + dst) = hv;
        *(short8*)(roiSl + dst) = lv;
    }
}

// ------ K2w: transpose + bf16-split [Wp|Ww] -> swizzled tiled (384x12544) ---
__global__ __launch_bounds__(256) void k_wsplit(
    const float* __restrict__ Wp,
    const float* __restrict__ Ww,
    unsigned short* __restrict__ WTsh,
    unsigned short* __restrict__ WTsl)
{
    __shared__ float tile[32][33];
    int k0 = blockIdx.x * 32, c0 = blockIdx.y * 32;
    int tx = threadIdx.x & 31, ty = threadIdx.x >> 5;

    #pragma unroll
    for (int i = 0; i < 4; ++i) {
        int k = k0 + ty + i * 8, c = c0 + tx;
        float v = (c < 256) ? Wp[(size_t)k * 256 + c] : Ww[(size_t)k * 128 + (c - 256)];
        tile[ty + i * 8][tx] = v;
    }
    __syncthreads();
    #pragma unroll
    for (int i = 0; i < 4; ++i) {
        int c = c0 + ty + i * 8, k = k0 + tx;
        float v = tile[tx][ty + i * 8];
        unsigned short hb = f2bf(v);
        float rem = v - bf2f(hb);
        int ct = c >> 7, rr = c & 127;
        size_t dst = ((size_t)(ct * KCH_TOT + (k >> 6)) * 128 + rr) * 64
                   + ((k & 63) ^ ((rr & 7) << 3));
        WTsh[dst] = hb;
        WTsl[dst] = f2bf(rem);
    }
}

// ------------- K2b: bf16x3 MFMA GEMM (MPAD2 x 384 x 12544), split-K ----------
__global__ __launch_bounds__(512, 4) void k_gemm_bf16x3(
    const unsigned short* __restrict__ roiSh,
    const unsigned short* __restrict__ roiSl,
    const unsigned short* __restrict__ WTsh,
    const unsigned short* __restrict__ WTsl,
    float* __restrict__ partials,      // (nseg, MPAD2, 384)
    int gch)
{
    __shared__ unsigned short aH[128 * 64], aL[128 * 64];
    __shared__ unsigned short bH[128 * 64], bL[128 * 64];

    const int nwg = gridDim.x;
    const int q8 = nwg >> 3, r8 = nwg & 7;
    const int xcd = blockIdx.x & 7, pos = blockIdx.x >> 3;
    const int start = (xcd < r8) ? xcd * (q8 + 1) : r8 * (q8 + 1) + (xcd - r8) * q8;
    const int lin = start + pos;
    const int mt = lin % MT_N;
    const int t2 = lin / MT_N;
    const int nt = t2 % NT_N;
    const int seg = t2 / NT_N;

    const int q0 = mt * 128, c0 = nt * 128;
    const int tid = threadIdx.x;
    const int lane = tid & 63;
    const int wid = tid >> 6;
    const int wm = wid >> 1, wn = wid & 1;
    const int lr = lane & 15, kb = lane >> 4;

    f32x4 acc[2][4];
    #pragma unroll
    for (int i = 0; i < 2; ++i)
        #pragma unroll
        for (int j = 0; j < 4; ++j) acc[i][j] = f32x4{0.f, 0.f, 0.f, 0.f};

    const char* Agh = (const char*)roiSh + (size_t)mt * KCH_TOT * 16384;
    const char* Agl = (const char*)roiSl + (size_t)mt * KCH_TOT * 16384;
    const char* Bgh = (const char*)WTsh + (size_t)nt * KCH_TOT * 16384;
    const char* Bgl = (const char*)WTsl + (size_t)nt * KCH_TOT * 16384;
    const int lb = wid * 2048;             // wave-uniform LDS byte base
    const int gl = lb + (lane << 4);       // per-lane global byte offset

    const int ch0 = seg * gch;

    for (int ch = 0; ch < gch; ++ch) {
        const size_t cb = (size_t)(ch0 + ch) * 16384;
        __syncthreads();   // previous chunk's LDS reads complete
        gld16(Agh + cb + gl,        (char*)aH + lb);
        gld16(Agh + cb + gl + 1024, (char*)aH + lb + 1024);
        gld16(Agl + cb + gl,        (char*)aL + lb);
        gld16(Agl + cb + gl + 1024, (char*)aL + lb + 1024);
        gld16(Bgh + cb + gl,        (char*)bH + lb);
        gld16(Bgh + cb + gl + 1024, (char*)bH + lb + 1024);
        gld16(Bgl + cb + gl,        (char*)bL + lb);
        gld16(Bgl + cb + gl + 1024, (char*)bL + lb + 1024);
        __syncthreads();   // drains vmcnt -> LDS ready
        mfma_32x64(aH, aL, bH, bL, wm, wn, lr, kb, acc);
    }

    #pragma unroll
    for (int i = 0; i < 2; ++i)
        #pragma unroll
        for (int j = 0; j < 4; ++j) {
            int q = q0 + wm * 32 + i * 16 + kb * 4;
            int c = c0 + wn * 64 + j * 16 + lr;
            #pragma unroll
            for (int e = 0; e < 4; ++e)
                partials[((size_t)seg * MPAD2 + q + e) * NDIM + c] = acc[i][j][e];
        }
}

// ---------- K2c: reduce partials + bias; tanh offsets; softmax weights -------
__global__ __launch_bounds__(384) void k_epilogue(
    const float* __restrict__ partials,   // (nseg, MPAD2, 384)
    const float* __restrict__ bp, const float* __restrict__ bw,
    float* __restrict__ pr,
    float* __restrict__ attn,
    int nseg)
{
    __shared__ float logit_s[128];
    int q = blockIdx.x;
    int t = threadIdx.x;
    float s = 0.f;
    for (int g = 0; g < nseg; ++g)
        s += partials[((size_t)g * MPAD2 + q) * NDIM + t];
    if (t < 256) {
        pr[(size_t)q * 256 + t] = tanhf(s + bp[t]);
    } else {
        logit_s[t - 256] = s + bw[t - 256];
    }
    __syncthreads();
    if (t < 128) {
        float v = logit_s[t];
        float m = v;
        #pragma unroll
        for (int off = 8; off >= 1; off >>= 1)
            m = fmaxf(m, __shfl_xor(m, off, 16));
        float e = expf(v - m);
        float sum = e;
        #pragma unroll
        for (int off = 8; off >= 1; off >>= 1)
            sum += __shfl_xor(sum, off, 16);
        attn[(size_t)q * 128 + t] = e / sum;
    }
}

// ------- FALLBACK K2 (round-1 fused kernel) used only if ws too small -------
__global__ __launch_bounds__(384) void k_roi_gemm(
    const float* __restrict__ value,
    const float* __restrict__ refp,
    const float* __restrict__ Wp,
    const float* __restrict__ bp,
    const float* __restrict__ Ww,
    const float* __restrict__ bw,
    float* __restrict__ pr_out,
    float* __restrict__ attn_out)
{
    __shared__ float roi_s[QPB][ROI_DIM];
    __shared__ float logit_s[QPB][128];

    int tid = threadIdx.x;
    int nq0 = blockIdx.x * QPB;

    for (int qi = 0; qi < QPB; ++qi) {
        int nq = nq0 + qi;
        int n = nq / LQ;
        const float* rp = refp + (size_t)nq * NL * 4;
        float cx = rp[0], cy = rp[1], w = rp[2], h = rp[3];
        float x1 = (cx - 0.5f * w) * W0 - 0.5f;
        float y1 = (cy - 0.5f * h) * H0 - 0.5f;
        float binw = w * W0 / ROI_;
        float binh = h * H0 / ROI_;
        const float* v0 = value + (size_t)n * LEN_IN * CDIM;

        for (int e = tid; e < ROI_DIM; e += 384) {
            int p = e >> 8;
            int ch = e & 255;
            int r = p / ROI_, c = p % ROI_;
            float sy = y1 + binh * (r + 0.5f);
            float sx = x1 + binw * (c + 0.5f);
            float y0f = floorf(sy), x0f = floorf(sx);
            float wy1 = sy - y0f, wx1 = sx - x0f;
            int y0 = (int)y0f, x0 = (int)x0f;
            float acc = 0.f;
            #pragma unroll
            for (int dy = 0; dy <= 1; ++dy)
                #pragma unroll
                for (int dx = 0; dx <= 1; ++dx) {
                    int yy = y0 + dy, xx = x0 + dx;
                    if (yy >= 0 && yy < H0 && xx >= 0 && xx < W0) {
                        float wgt = (dy ? wy1 : 1.f - wy1) * (dx ? wx1 : 1.f - wx1);
                        acc += wgt * v0[((size_t)(yy * W0 + xx)) * CDIM + ch];
                    }
                }
            roi_s[qi][e] = acc;
        }
    }
    __syncthreads();

    int col = tid;
    const float* Wsel;
    int stride;
    float bias;
    if (col < 256) { Wsel = Wp + col;         stride = 256; bias = bp[col]; }
    else           { Wsel = Ww + (col - 256); stride = 128; bias = bw[col - 256]; }

    float acc0 = 0.f, acc1 = 0.f, acc2 = 0.f;
    const float* wptr = Wsel;
    #pragma unroll 8
    for (int k = 0; k < ROI_DIM; ++k) {
        float wv = *wptr; wptr += stride;
        acc0 += roi_s[0][k] * wv;
        acc1 += roi_s[1][k] * wv;
        acc2 += roi_s[2][k] * wv;
    }
    acc0 += bias; acc1 += bias; acc2 += bias;

    if (col < 256) {
        pr_out[(size_t)(nq0 + 0) * 256 + col] = tanhf(acc0);
        pr_out[(size_t)(nq0 + 1) * 256 + col] = tanhf(acc1);
        pr_out[(size_t)(nq0 + 2) * 256 + col] = tanhf(acc2);
    } else {
        int j = col - 256;
        logit_s[0][j] = acc0;
        logit_s[1][j] = acc1;
        logit_s[2][j] = acc2;
    }
    __syncthreads();

    {
        int i = tid & 15;
        int g = tid >> 4;
        int qi = g >> 3, h = g & 7;
        float v = logit_s[qi][h * 16 + i];
        float m = v;
        #pragma unroll
        for (int off = 8; off >= 1; off >>= 1)
            m = fmaxf(m, __shfl_xor(m, off, 16));
        float e = expf(v - m);
        float s = e;
        #pragma unroll
        for (int off = 8; off >= 1; off >>= 1)
            s += __shfl_xor(s, off, 16);
        attn_out[(size_t)(nq0 + qi) * 128 + h * 16 + i] = e / s;
    }
}

// --------- K3: multi-scale deformable sampling + weighted sum ----------
__global__ __launch_bounds__(256) void k_sample(
    const float* __restrict__ value,
    const float* __restrict__ refp,
    const float* __restrict__ pr,
    const float* __restrict__ attn,
    float* __restrict__ out_attn)
{
    int nq = blockIdx.x;
    int n = nq / LQ;
    int tid = threadIdx.x;
    int h = tid >> 5, dh = tid & 31;

    float acc = 0.f;
    for (int l = 0; l < NL; ++l) {
        const float* rp = refp + ((size_t)nq * NL + l) * 4;
        float cx = rp[0], cy = rp[1], rw = rp[2], rh = rp[3];
        int Hl = d_HL[l], Wl = d_WL[l], s = d_ST[l];
        const float* vl = value + ((size_t)n * LEN_IN + s) * CDIM;

        #pragma unroll
        for (int p = 0; p < NP; ++p) {
            float prx = pr[(size_t)nq * 256 + h * 32 + l * 8 + p * 2 + 0];
            float pry = pr[(size_t)nq * 256 + h * 32 + l * 8 + p * 2 + 1];
            float a   = attn[(size_t)nq * 128 + h * 16 + l * 4 + p];
            float px = (cx + prx * rw * 0.5f) * Wl - 0.5f;
            float py = (cy + pry * rh * 0.5f) * Hl - 0.5f;
            float x0f = floorf(px), y0f = floorf(py);
            float wx1 = px - x0f, wy1 = py - y0f;
            int x0 = (int)x0f, y0 = (int)y0f;
            float sv = 0.f;
            #pragma unroll
            for (int dy = 0; dy <= 1; ++dy)
                #pragma unroll
                for (int dx = 0; dx <= 1; ++dx) {
                    int yy = y0 + dy, xx = x0 + dx;
                    if (yy >= 0 && yy < Hl && xx >= 0 && xx < Wl) {
                        float wgt = (dy ? wy1 : 1.f - wy1) * (dx ? wx1 : 1.f - wx1);
                        sv += wgt * vl[((size_t)(yy * Wl + xx)) * CDIM + h * 32 + dh];
                    }
                }
            acc += a * sv;
        }
    }
    out_attn[(size_t)nq * CDIM + tid] = acc;
}

// ---------------- K4: out = out_attn @ Wo + bo (300 blocks x 4 rows) --------
__global__ __launch_bounds__(256) void k_out_proj(
    const float* __restrict__ x,
    const float* __restrict__ Wo,
    const float* __restrict__ bo,
    float* __restrict__ out)
{
    const int ROWS = 4;
    __shared__ float a_s[ROWS][CDIM];
    int row0 = blockIdx.x * ROWS;
    int tid = threadIdx.x;

    #pragma unroll
    for (int r = 0; r < ROWS; ++r)
        a_s[r][tid] = x[(size_t)(row0 + r) * CDIM + tid];
    __syncthreads();

    float acc[ROWS];
    #pragma unroll
    for (int r = 0; r < ROWS; ++r) acc[r] = 0.f;

    for (int k = 0; k < CDIM; k += 4) {
        float w0 = Wo[(k + 0) * CDIM + tid];
        float w1 = Wo[(k + 1) * CDIM + tid];
        float w2 = Wo[(k + 2) * CDIM + tid];
        float w3 = Wo[(k + 3) * CDIM + tid];
        #pragma unroll
        for (int r = 0; r < ROWS; ++r) {
            float4 av = *(const float4*)&a_s[r][k];
            acc[r] = fmaf(av.x, w0, fmaf(av.y, w1, fmaf(av.z, w2, fmaf(av.w, w3, acc[r]))));
        }
    }
    float b = bo[tid];
    #pragma unroll
    for (int r = 0; r < ROWS; ++r)
        out[(size_t)(row0 + r) * CDIM + tid] = acc[r] + b;
}

extern "C" void kernel_launch(void* const* d_in, const int* in_sizes, int n_in,
                              void* d_out, int out_size, void* d_ws, size_t ws_size,
                              hipStream_t stream) {
    const float* refp = (const float*)d_in[1];
    const float* inp  = (const float*)d_in[2];
    const unsigned char* mask = (const unsigned char*)d_in[5];
    const float* Wv = (const float*)d_in[6];
    const float* bv = (const float*)d_in[7];
    const float* Wp = (const float*)d_in[8];
    const float* bp = (const float*)d_in[9];
    const float* Ww = (const float*)d_in[10];
    const float* bw = (const float*)d_in[11];
    const float* Wo = (const float*)d_in[12];
    const float* bo = (const float*)d_in[13];
    float* out = (float*)d_out;

    // workspace layout (fixed part)
    char* ws = (char*)d_ws;
    constexpr size_t VALUE_BYTES = (size_t)VTOT * CDIM * 4;               // 81,702,912
    constexpr size_t ROI_BYTES   = (size_t)MPAD2 * ROI_DIM * 2;           // 32,112,640
    constexpr size_t WT_BYTES    = (size_t)NDIM * ROI_DIM * 2;            //  9,633,792
    constexpr size_t WVT_BYTES   = (size_t)CDIM * CDIM * 2;               //    131,072
    constexpr size_t SEG_BYTES   = (size_t)MPAD2 * NDIM * 4;              //  1,966,080
    constexpr size_t PR_BYTES    = (size_t)NQ_TOT * 256 * 4;
    constexpr size_t ATTN_BYTES  = (size_t)NQ_TOT * 128 * 4;
    constexpr size_t OA_BYTES    = (size_t)NQ_TOT * 256 * 4;

    size_t off = 0;
    float* value = (float*)(ws + off);                  off += VALUE_BYTES;
    unsigned short* roiSh = (unsigned short*)(ws + off); off += ROI_BYTES;
    unsigned short* roiSl = (unsigned short*)(ws + off); off += ROI_BYTES;
    unsigned short* WTsh  = (unsigned short*)(ws + off); off += WT_BYTES;
    unsigned short* WTsl  = (unsigned short*)(ws + off); off += WT_BYTES;
    unsigned short* WvTsh = (unsigned short*)(ws + off); off += WVT_BYTES;
    unsigned short* WvTsl = (unsigned short*)(ws + off); off += WVT_BYTES;
    const size_t fixed_end = off;
    const size_t tail = PR_BYTES + ATTN_BYTES + OA_BYTES;

    // choose split-K depth by workspace headroom (nseg must divide 196)
    int nseg = 0;
    if (ws_size >= fixed_end + 14 * SEG_BYTES + tail)      nseg = 14;
    else if (ws_size >= fixed_end + 7 * SEG_BYTES + tail)  nseg = 7;

    if (nseg > 0) {
        float* partials = (float*)(ws + fixed_end);
        size_t o2 = fixed_end + (size_t)nseg * SEG_BYTES;
        float* pr       = (float*)(ws + o2); o2 += PR_BYTES;
        float* attn     = (float*)(ws + o2); o2 += ATTN_BYTES;
        float* out_attn = (float*)(ws + o2);

        // K1: Wv split (swizzled tiled) + MFMA value projection (B gload_lds)
        k_wvsplit<<<dim3(CDIM / 32, CDIM / 32), 256, 0, stream>>>(Wv, WvTsh, WvTsl);
        k_value_mfma<<<dim3(2, VMT), 512, 0, stream>>>(inp, mask, WvTsh, WvTsl, bv, value);
        // K2a: ROI align -> bf16 hi/lo, swizzled tiled layout (1200 blocks)
        k_roi_split<<<NQ_TOT, 256, 0, stream>>>(value, refp, roiSh, roiSl);
        // K2w: W transpose + split, swizzled tiled layout
        k_wsplit<<<dim3(ROI_DIM / 32, NDIM / 32), 256, 0, stream>>>(Wp, Ww, WTsh, WTsl);
        // K2b: bf16x3 MFMA GEMM, split-K, XCD swizzle, global_load_lds staging
        k_gemm_bf16x3<<<MT_N * NT_N * nseg, 512, 0, stream>>>(
            roiSh, roiSl, WTsh, WTsl, partials, KCH_TOT / nseg);
        // K2c: epilogue
        k_epilogue<<<NQ_TOT, 384, 0, stream>>>(partials, bp, bw, pr, attn, nseg);
        // K3 + K4
        k_sample<<<NQ_TOT, 256, 0, stream>>>(value, refp, pr, attn, out_attn);
        k_out_proj<<<NQ_TOT / 4, 256, 0, stream>>>(out_attn, Wo, bo, out);
    } else {
        // fallback: round-1/2 path (small ws)
        float* pr       = (float*)(ws + VALUE_BYTES);
        float* attn     = (float*)(ws + VALUE_BYTES + PR_BYTES);
        float* out_attn = (float*)(ws + VALUE_BYTES + PR_BYTES + ATTN_BYTES);
        k_value_proj<<<(VTOT + 15) / 16, 256, 0, stream>>>(inp, mask, Wv, bv, value);
        k_roi_gemm<<<NQ_TOT / QPB, 384, 0, stream>>>(value, refp, Wp, bp, Ww, bw, pr, attn);
        k_sample<<<NQ_TOT, 256, 0, stream>>>(value, refp, pr, attn, out_attn);
        k_out_proj<<<NQ_TOT / 4, 256, 0, stream>>>(out_attn, Wo, bo, out);
    }
}